// Round 13
// baseline (152.403 us; speedup 1.0000x reference)
//
#include <hip/hip_runtime.h>
#include <math.h>

// Problem constants
//  B=8, C_IN=80, T=1000, D_MODEL=256, D_INNER=512, D_STATE=16, DT_RANK=16,
//  D_CONV=4, N_LABELS=35

// ---- workspace layout (float offsets) ----
#define OFF_W1T    0         // [80][1024]  folded (in_proj@proj) transposed
#define OFF_B1     81920     // [1024]      folded bias
#define OFF_W2S    82944     // [35][512]   (fc_w@out_proj_w) * 1e-3 (mean fold)
#define OFF_AL2    100864    // [512][16]   A = -exp(A_log)
#define OFF_XH     109056    // [8000][512] silu(conv(xh)) — live through k3
#define OFF_SZ     4205056   // [8000][512] silu(z)       — live through k3
#define OFF_CHUNKA 8301056   // [16ck][8b][16s][512d] float4 (P,q,S1,S2)
#define OFF_ACC16  12495360  // [16ck][8b][512d] xh*sz partials
#define OFF_DBCP   12560896  // [2ks][8000][48] k2b partials
#define OFF_YBAR   18878976  // [8][512]
#define WS_FLOATS  18883072  // ~75.5 MB

#define CK_FLOATS 262144
#define CHUNK_BASE(ck) (OFF_CHUNKA + (ck) * CK_FLOATS)

__device__ __forceinline__ float silu_f(float v) {
  return v / (1.f + __expf(-v));
}

// ================= prep (merged): W1T fold + small tables ==================
__global__ __launch_bounds__(256) void prep_all(const float* __restrict__ proj_w,
                                                const float* __restrict__ proj_b,
                                                const float* __restrict__ in_proj_w,
                                                const float* __restrict__ fc_w,
                                                const float* __restrict__ out_proj_w,
                                                const float* __restrict__ A_log,
                                                float* __restrict__ ws) {
  const int tid = threadIdx.x;
  if (blockIdx.x < 80) {
    // W1T[c][n] = sum_m in_proj_w[n][m] * proj_w[m][c]
    const int nt = blockIdx.x / 5;      // 16 tiles of 64 n
    const int ct = blockIdx.x % 5;      // 5 tiles of 16 c
    const int n0 = nt * 64, c0 = ct * 16;
    __shared__ float Pl[16 * 68];       // [c][k]
    __shared__ float Il[64 * 68];       // [k][n]
    const int ng = tid & 31, cg = tid >> 5;
    float acc[2][2] = {{0.f, 0.f}, {0.f, 0.f}};
    for (int kc = 0; kc < 256; kc += 64) {
      __syncthreads();
      for (int i = tid; i < 16 * 64; i += 256) {
        int k = i >> 4, c = i & 15;
        Pl[c * 68 + k] = proj_w[(kc + k) * 80 + c0 + c];
      }
      for (int i = tid; i < 64 * 64; i += 256) {
        int n = i >> 6, k = i & 63;
        Il[k * 68 + n] = in_proj_w[(n0 + n) * 256 + kc + k];
      }
      __syncthreads();
      for (int k = 0; k < 64; ++k) {
        float p0 = Pl[(cg * 2 + 0) * 68 + k];
        float p1 = Pl[(cg * 2 + 1) * 68 + k];
        float2 iv = *(const float2*)&Il[k * 68 + ng * 2];
        acc[0][0] = fmaf(p0, iv.x, acc[0][0]);
        acc[0][1] = fmaf(p0, iv.y, acc[0][1]);
        acc[1][0] = fmaf(p1, iv.x, acc[1][0]);
        acc[1][1] = fmaf(p1, iv.y, acc[1][1]);
      }
    }
    for (int r = 0; r < 2; ++r)
      for (int q = 0; q < 2; ++q)
        ws[OFF_W1T + (c0 + cg * 2 + r) * 1024 + n0 + ng * 2 + q] = acc[r][q];
  } else {
    int idx = (blockIdx.x - 80) * 256 + tid;
    if (idx < 1024) {
      float s = 0.f;
      for (int m = 0; m < 256; ++m) s = fmaf(in_proj_w[idx * 256 + m], proj_b[m], s);
      ws[OFF_B1 + idx] = s;
    } else if (idx < 1024 + 17920) {
      int j = idx - 1024;
      int n = j / 512, d = j - n * 512;
      float s = 0.f;
      for (int m = 0; m < 256; ++m) s = fmaf(fc_w[n * 256 + m], out_proj_w[m * 512 + d], s);
      ws[OFF_W2S + j] = s * 1e-3f;      // fold mean over T=1000
    } else if (idx < 1024 + 17920 + 8192) {
      int j = idx - (1024 + 17920);
      ws[OFF_AL2 + j] = -expf(A_log[j]);
    }
  }
}

// ================= K1: xz = X @ W1T + b1, 4-col named-scalar tile ==========
// Fix 1 (r13): xs hoisted to KERNEL scope — the templated device fn had its
//   own __shared__ per instantiation -> LDS_Block 23040 (2x) -> Occ 23%.
// Fix 2 (r13): W1T loads as distance-2 pipeline — 44 FMA (~88cyc) per k
//   couldn't cover ~200cyc L2 latency at distance 1 (VALUBusy 41% == 88/198).

__device__ __forceinline__ void k1_epil_h(int d, int b, int tw0,
    const float* __restrict__ conv_w, const float* __restrict__ conv_b,
    float* __restrict__ ws, bool zeroL,
    float a1, float a2, float a3, float a4, float a5, float a6,
    float a7, float a8, float a9, float a10, float a11) {
  if (zeroL) { a1 = 0.f; a2 = 0.f; a3 = 0.f; }   // xz[t<0] = 0
  const float4 cw = *(const float4*)&conv_w[d * 4];
  const float cb = conv_b[d];
  float s[11] = {a1, a2, a3, a4, a5, a6, a7, a8, a9, a10, a11};
#pragma unroll
  for (int i = 0; i < 8; ++i) {
    float v = cb;
    v = fmaf(cw.x, s[i + 0], v);
    v = fmaf(cw.y, s[i + 1], v);
    v = fmaf(cw.z, s[i + 2], v);
    v = fmaf(cw.w, s[i + 3], v);
    int t = tw0 + i;
    if (t < 1000) ws[OFF_XH + (b * 1000 + t) * 512 + d] = silu_f(v);
  }
}

__device__ __forceinline__ void k1_epil_z(int d0, int b, int tw0,
    float* __restrict__ ws,
    float a4, float a5, float a6, float a7, float a8, float a9,
    float a10, float a11) {
  float s[8] = {a4, a5, a6, a7, a8, a9, a10, a11};
#pragma unroll
  for (int i = 0; i < 8; ++i) {
    int t = tw0 + i;
    if (t < 1000) ws[OFF_SZ + (b * 1000 + t) * 512 + d0] = silu_f(s[i]);
  }
}

#define K1_DECL(c)                                                          \
  float A##c##1, A##c##2, A##c##3, A##c##4, A##c##5, A##c##6, A##c##7,      \
        A##c##8, A##c##9, A##c##10, A##c##11;                               \
  {                                                                         \
    const float b1v = ws[OFF_B1 + nb + 64 * (c)];                           \
    A##c##1 = b1v; A##c##2 = b1v; A##c##3 = b1v; A##c##4 = b1v;             \
    A##c##5 = b1v; A##c##6 = b1v; A##c##7 = b1v; A##c##8 = b1v;             \
    A##c##9 = b1v; A##c##10 = b1v; A##c##11 = b1v;                          \
  }

#define K1_FMA(c, W)                                                        \
  if (CONVHALF) {                                                           \
    A##c##1 = fmaf(x1, (W), A##c##1);                                       \
    A##c##2 = fmaf(x2, (W), A##c##2);                                       \
    A##c##3 = fmaf(x3, (W), A##c##3);                                       \
  }                                                                         \
  A##c##4  = fmaf(x4,  (W), A##c##4);                                       \
  A##c##5  = fmaf(x5,  (W), A##c##5);                                       \
  A##c##6  = fmaf(x6,  (W), A##c##6);                                       \
  A##c##7  = fmaf(x7,  (W), A##c##7);                                       \
  A##c##8  = fmaf(x8,  (W), A##c##8);                                       \
  A##c##9  = fmaf(x9,  (W), A##c##9);                                       \
  A##c##10 = fmaf(x10, (W), A##c##10);                                      \
  A##c##11 = fmaf(x11, (W), A##c##11);

template <bool CONVHALF>
__device__ __forceinline__ void k1_body(const float* __restrict__ xs,
                                        const float* __restrict__ conv_w,
                                        const float* __restrict__ conv_b,
                                        float* __restrict__ ws,
                                        int nt, int tcb, int b) {
  const int tid = threadIdx.x;
  const int lane = tid & 63;
  const int wv = tid >> 6;            // wave's t-subchunk 0..3
  const int t0b = tcb * 32;
  const int tw0 = t0b + wv * 8;

  const int nb = nt * 256 + lane;     // thread's cols: nb + 64c, c=0..3
  K1_DECL(0) K1_DECL(1) K1_DECL(2) K1_DECL(3)

  const float* __restrict__ wp = ws + OFF_W1T + nb;
  const int woff = wv * 8;

  // distance-2 W pipeline: batch A = k, batch B = k+1, prefetch k+2
  float pa0 = wp[0],    pa1 = wp[64],      pa2 = wp[128],      pa3 = wp[192];
  float pb0 = wp[1024], pb1 = wp[1024+64], pb2 = wp[1024+128], pb3 = wp[1024+192];
  for (int k = 0; k < 80; ++k) {
    const float c0 = pa0, c1 = pa1, c2 = pa2, c3 = pa3;
    pa0 = pb0; pa1 = pb1; pa2 = pb2; pa3 = pb3;
    if (k < 78) {
      const float* wn = wp + (k + 2) * 1024;
      pb0 = wn[0]; pb1 = wn[64]; pb2 = wn[128]; pb3 = wn[192];
    }
    float x1, x2, x3;
    if (CONVHALF) {
      float4 xa = *(const float4*)&xs[k * 36 + woff];       // broadcast b128
      x1 = xa.y; x2 = xa.z; x3 = xa.w;
    } else {
      x1 = 0.f; x2 = 0.f; x3 = 0.f;
    }
    float4 xb = *(const float4*)&xs[k * 36 + woff + 4];
    float4 xc = *(const float4*)&xs[k * 36 + woff + 8];
    const float x4 = xb.x, x5 = xb.y, x6 = xb.z, x7 = xb.w;
    const float x8 = xc.x, x9 = xc.y, x10 = xc.z, x11 = xc.w;
    K1_FMA(0, c0) K1_FMA(1, c1) K1_FMA(2, c2) K1_FMA(3, c3)
  }

  const bool zeroL = (tcb == 0 && wv == 0);
  if (CONVHALF) {
    k1_epil_h(nb + 0,   b, tw0, conv_w, conv_b, ws, zeroL,
              A01, A02, A03, A04, A05, A06, A07, A08, A09, A010, A011);
    k1_epil_h(nb + 64,  b, tw0, conv_w, conv_b, ws, zeroL,
              A11, A12, A13, A14, A15, A16, A17, A18, A19, A110, A111);
    k1_epil_h(nb + 128, b, tw0, conv_w, conv_b, ws, zeroL,
              A21, A22, A23, A24, A25, A26, A27, A28, A29, A210, A211);
    k1_epil_h(nb + 192, b, tw0, conv_w, conv_b, ws, zeroL,
              A31, A32, A33, A34, A35, A36, A37, A38, A39, A310, A311);
  } else {
    const int d0 = nb - 512;
    k1_epil_z(d0 + 0,   b, tw0, ws, A04, A05, A06, A07, A08, A09, A010, A011);
    k1_epil_z(d0 + 64,  b, tw0, ws, A14, A15, A16, A17, A18, A19, A110, A111);
    k1_epil_z(d0 + 128, b, tw0, ws, A24, A25, A26, A27, A28, A29, A210, A211);
    k1_epil_z(d0 + 192, b, tw0, ws, A34, A35, A36, A37, A38, A39, A310, A311);
  }
}

__global__ __launch_bounds__(256, 2) void k1_xz(const float* __restrict__ x,
                                                const float* __restrict__ conv_w,
                                                const float* __restrict__ conv_b,
                                                float* __restrict__ ws) {
  const int nt  = blockIdx.x;   // 0,1: conv half; 2,3: z half
  const int tcb = blockIdx.y;   // 32 t-blocks of 32
  const int b   = blockIdx.z;
  const int tid = threadIdx.x;
  const int t0b = tcb * 32;

  // single kernel-scope x tile [80][36] covering t = t0b-4 .. t0b+31
  __shared__ __align__(16) float xs[80 * 36];
  for (int i = tid; i < 2880; i += 256) {
    int k = i / 36, j = i - k * 36;
    int t = t0b - 4 + j;
    float v = 0.f;
    if (t >= 0 && t < 1000) v = x[(b * 80 + k) * 1000 + t];
    xs[i] = v;
  }
  __syncthreads();

  if (nt < 2) k1_body<true >(xs, conv_w, conv_b, ws, nt, tcb, b);
  else        k1_body<false>(xs, conv_w, conv_b, ws, nt, tcb, b);
}

// ================= K2b: dbc partials = xh @ x_proj_w.T (split-K x2) =========
__global__ __launch_bounds__(256) void k2b_dbc(const float* __restrict__ x_proj_w,
                                               float* __restrict__ ws) {
  const int row0 = blockIdx.x * 16;
  const int ks   = blockIdx.y;          // K half
  const int k0   = ks * 256;
  __shared__ float Xl[16 * 68];
  __shared__ float Wl[48 * 68];
  const int tid = threadIdx.x;
  const int ng = tid & 15, rg = tid >> 4;
  float acc[3] = {0.f, 0.f, 0.f};
  for (int kc = 0; kc < 256; kc += 64) {
    __syncthreads();
    for (int i = tid; i < 16 * 64; i += 256) {
      int r = i >> 6, c = i & 63;
      Xl[r * 68 + c] = ws[OFF_XH + (row0 + r) * 512 + k0 + kc + c];
    }
    for (int i = tid; i < 48 * 64; i += 256) {
      int r = i >> 6, c = i & 63;
      Wl[r * 68 + c] = x_proj_w[r * 512 + k0 + kc + c];
    }
    __syncthreads();
    for (int c = 0; c < 64; c += 4) {
      float4 xa = *(const float4*)&Xl[rg * 68 + c];
      float4 w0 = *(const float4*)&Wl[(ng * 3 + 0) * 68 + c];
      float4 w1 = *(const float4*)&Wl[(ng * 3 + 1) * 68 + c];
      float4 w2 = *(const float4*)&Wl[(ng * 3 + 2) * 68 + c];
      acc[0] += xa.x*w0.x + xa.y*w0.y + xa.z*w0.z + xa.w*w0.w;
      acc[1] += xa.x*w1.x + xa.y*w1.y + xa.z*w1.z + xa.w*w1.w;
      acc[2] += xa.x*w2.x + xa.y*w2.y + xa.z*w2.z + xa.w*w2.w;
    }
  }
  for (int n = 0; n < 3; ++n)
    ws[OFF_DBCP + ks * 384000 + (row0 + rg) * 48 + ng * 3 + n] = acc[n];
}

// ================= K3: fused delta + chunked scan pass 1 ====================
__global__ __launch_bounds__(512) void k3_scan1(const float* __restrict__ dt_proj_w,
                                                const float* __restrict__ dt_proj_b,
                                                float* __restrict__ ws) {
  const int dg = blockIdx.x;          // 8 groups of 64 d
  const int ck = blockIdx.y;          // 16 t-chunks (63 for ck<8, else 62)
  const int b  = blockIdx.z;
  const int tid = threadIdx.x;
  const int lane = tid & 63;
  const int wv = tid >> 6;
  const int d = dg * 64 + lane;
  const int nt = (ck < 8) ? 63 : 62;
  const int tstart = (ck < 8) ? 63 * ck : 62 * ck + 8;
  const int rowbase = b * 1000 + tstart;

  __shared__ __align__(16) float dbcl[63 * 48];   // [t][dt(16)|B(16)|C(16)]
  __shared__ float dlt[63 * 64];                  // [t][d-lane] delta
  for (int i = tid; i < nt * 48; i += 512)
    dbcl[i] = ws[OFF_DBCP + rowbase * 48 + i] +
              ws[OFF_DBCP + 384000 + rowbase * 48 + i];
  __syncthreads();

  {
    const float4* wp = (const float4*)(dt_proj_w + d * 16);
    const float4 w0 = wp[0], w1 = wp[1], w2 = wp[2], w3 = wp[3];
    const float bias = dt_proj_b[d];
    const int tend = (wv * 8 + 8 < nt) ? wv * 8 + 8 : nt;
    for (int tt = wv * 8; tt < tend; ++tt) {
      const float* dr = &dbcl[tt * 48];
      float4 q0 = *(const float4*)(dr + 0);       // explicit b128 broadcasts
      float4 q1 = *(const float4*)(dr + 4);
      float4 q2 = *(const float4*)(dr + 8);
      float4 q3 = *(const float4*)(dr + 12);
      float lin = bias;
      lin = fmaf(q0.x, w0.x, lin); lin = fmaf(q0.y, w0.y, lin);
      lin = fmaf(q0.z, w0.z, lin); lin = fmaf(q0.w, w0.w, lin);
      lin = fmaf(q1.x, w1.x, lin); lin = fmaf(q1.y, w1.y, lin);
      lin = fmaf(q1.z, w1.z, lin); lin = fmaf(q1.w, w1.w, lin);
      lin = fmaf(q2.x, w2.x, lin); lin = fmaf(q2.y, w2.y, lin);
      lin = fmaf(q2.z, w2.z, lin); lin = fmaf(q2.w, w2.w, lin);
      lin = fmaf(q3.x, w3.x, lin); lin = fmaf(q3.y, w3.y, lin);
      lin = fmaf(q3.z, w3.z, lin); lin = fmaf(q3.w, w3.w, lin);
      dlt[tt * 64 + lane] = fmaxf(lin, 0.f) + log1pf(__expf(-fabsf(lin)));
    }
  }
  __syncthreads();

  const float2 av = *(const float2*)&ws[OFF_AL2 + d * 16 + wv * 2];
  const float a0 = av.x, a1 = av.y;
  const float* __restrict__ xhp = ws + OFF_XH + rowbase * 512 + d;
  const float* __restrict__ szp = ws + OFF_SZ + rowbase * 512 + d;
  float h0 = 0.f, h1 = 0.f, cp0 = 1.f, cp1 = 1.f;
  float S10 = 0.f, S11 = 0.f, S20 = 0.f, S21 = 0.f, xacc = 0.f;
#pragma unroll 4
  for (int i = 0; i < nt; ++i) {
    float del = dlt[i * 64 + lane];
    float xh  = xhp[i * 512];
    float sz  = szp[i * 512];
    float2 bB = *(const float2*)&dbcl[i * 48 + 16 + wv * 2];
    float2 bC = *(const float2*)&dbcl[i * 48 + 32 + wv * 2];
    float du = del * xh;
    xacc = fmaf(xh, sz, xacc);
    float e0 = __expf(del * a0), e1 = __expf(del * a1);
    cp0 *= e0; cp1 *= e1;
    h0 = fmaf(e0, h0, du * bB.x);
    h1 = fmaf(e1, h1, du * bB.y);
    float cs0 = bC.x * sz, cs1 = bC.y * sz;
    S10 = fmaf(h0, cs0, S10); S11 = fmaf(h1, cs1, S11);
    S20 = fmaf(cp0, cs0, S20); S21 = fmaf(cp1, cs1, S21);
  }
  {
    const int cbase = CHUNK_BASE(ck);
    const int s = wv * 2;
    int idx = (b * 16 + s) * 512 + d;
    *(float4*)&ws[cbase + idx * 4] = make_float4(cp0, h0, S10, S20);
    *(float4*)&ws[cbase + (idx + 512) * 4] = make_float4(cp1, h1, S11, S21);
  }
  if (wv == 0) ws[OFF_ACC16 + (ck * 8 + b) * 512 + d] = xacc;
}

// ================= K4: combine 16 chunks + s-reduce -> ybar =================
__global__ __launch_bounds__(256) void k4_scan2(const float* __restrict__ Dvec,
                                                float* __restrict__ ws) {
  const int dg = blockIdx.x;   // 32 groups of 16 d
  const int b  = blockIdx.y;
  const int tid = threadIdx.x;
  const int dl = tid & 15, s = tid >> 4;
  const int d = dg * 16 + dl;
  const int lane = tid & 63, wv = tid >> 6;
  float h = 0.f, y = 0.f;
#pragma unroll
  for (int k = 0; k < 16; ++k) {
    const float4 f = *(const float4*)&ws[CHUNK_BASE(k) + ((b * 16 + s) * 512 + d) * 4];
    y = fmaf(f.w, h, y + f.z);   // S1 + S2*h_in
    h = fmaf(f.x, h, f.y);       // P*h_in + q
  }
  y += __shfl_xor(y, 16);
  y += __shfl_xor(y, 32);
  __shared__ float ys[4][16];
  if (lane < 16) ys[wv][dl] = y;
  __syncthreads();
  if (tid < 16) {
    float yt = ys[0][tid] + ys[1][tid] + ys[2][tid] + ys[3][tid];
    float acc = 0.f;
#pragma unroll
    for (int k = 0; k < 16; ++k) acc += ws[OFF_ACC16 + (k * 8 + b) * 512 + dg * 16 + tid];
    int dd = dg * 16 + tid;
    ws[OFF_YBAR + b * 512 + dd] = yt + Dvec[dd] * acc;
  }
}

// ================= K5: out = ybar @ W2s.T + fc_b =================
__global__ __launch_bounds__(64) void k5_out(const float* __restrict__ fc_b,
                                             const float* __restrict__ ws,
                                             float* __restrict__ out) {
  const int b = blockIdx.x;
  const int n = threadIdx.x;
  if (n >= 35) return;
  const float* yb = ws + OFF_YBAR + b * 512;
  const float* w  = ws + OFF_W2S + n * 512;
  float sum = 0.f;
#pragma unroll 8
  for (int k = 0; k < 512; ++k) sum = fmaf(yb[k], w[k], sum);
  out[b * 35 + n] = sum + fc_b[n];
}

extern "C" void kernel_launch(void* const* d_in, const int* in_sizes, int n_in,
                              void* d_out, int out_size, void* d_ws, size_t ws_size,
                              hipStream_t stream) {
  const float* x          = (const float*)d_in[0];
  const float* proj_w     = (const float*)d_in[1];
  const float* proj_b     = (const float*)d_in[2];
  const float* in_proj_w  = (const float*)d_in[3];
  const float* conv_w     = (const float*)d_in[4];
  const float* conv_b     = (const float*)d_in[5];
  const float* x_proj_w   = (const float*)d_in[6];
  const float* dt_proj_w  = (const float*)d_in[7];
  const float* dt_proj_b  = (const float*)d_in[8];
  const float* A_log      = (const float*)d_in[9];
  const float* Dvec       = (const float*)d_in[10];
  const float* out_proj_w = (const float*)d_in[11];
  const float* fc_w       = (const float*)d_in[12];
  const float* fc_b       = (const float*)d_in[13];
  float* ws  = (float*)d_ws;
  float* out = (float*)d_out;
  if (ws_size < (size_t)WS_FLOATS * sizeof(float)) return;  // need ~76 MB scratch

  prep_all  <<<186,            256, 0, stream>>>(proj_w, proj_b, in_proj_w, fc_w,
                                                 out_proj_w, A_log, ws);
  k1_xz     <<<dim3(4, 32, 8), 256, 0, stream>>>(x, conv_w, conv_b, ws);
  k2b_dbc   <<<dim3(500, 2),   256, 0, stream>>>(x_proj_w, ws);
  k3_scan1  <<<dim3(8, 16, 8), 512, 0, stream>>>(dt_proj_w, dt_proj_b, ws);
  k4_scan2  <<<dim3(32, 8),    256, 0, stream>>>(Dvec, ws);
  k5_out    <<<8,              64,  0, stream>>>(fc_b, ws, out);
}

// Round 14
// 139.897 us; speedup vs baseline: 1.0894x; 1.0894x over previous
//
#include <hip/hip_runtime.h>
#include <math.h>

// Problem constants
//  B=8, C_IN=80, T=1000, D_MODEL=256, D_INNER=512, D_STATE=16, DT_RANK=16,
//  D_CONV=4, N_LABELS=35

// ---- workspace layout (float offsets) ----
#define OFF_W1T    0         // [80][1024]  folded (in_proj@proj) transposed
#define OFF_B1     81920     // [1024]      folded bias
#define OFF_W2S    82944     // [35][512]   (fc_w@out_proj_w) * 1e-3 (mean fold)
#define OFF_AL2    100864    // [512][16]   A = -exp(A_log)
#define OFF_XH     109056    // [8000][512] silu(conv(xh)) — live through k3
#define OFF_SZ     4205056   // [8000][512] silu(z)       — live through k3
#define OFF_CHUNKA 8301056   // [20ck][8b][16s][512d] float4 (P,q,S1,S2) = 5,242,880 floats
#define OFF_ACC20  13543936  // [20ck][8b][512d] xh*sz partials = 81,920 floats
#define OFF_DBCP   13625856  // [2ks][8000][48] k2b partials = 768,000 floats (ends 14,393,856)
#define OFF_YBAR   18878976  // [8][512]
#define WS_FLOATS  18883072  // ~75.5 MB

#define CK_FLOATS 262144
#define CHUNK_BASE(ck) (OFF_CHUNKA + (ck) * CK_FLOATS)
#define K3_NT 50             // 20 chunks x 50 t = 1000 — COMPILE-TIME trip count

__device__ __forceinline__ float silu_f(float v) {
  return v / (1.f + __expf(-v));
}

// ================= prep (merged): W1T fold + small tables ==================
__global__ __launch_bounds__(256) void prep_all(const float* __restrict__ proj_w,
                                                const float* __restrict__ proj_b,
                                                const float* __restrict__ in_proj_w,
                                                const float* __restrict__ fc_w,
                                                const float* __restrict__ out_proj_w,
                                                const float* __restrict__ A_log,
                                                float* __restrict__ ws) {
  const int tid = threadIdx.x;
  if (blockIdx.x < 80) {
    // W1T[c][n] = sum_m in_proj_w[n][m] * proj_w[m][c]
    const int nt = blockIdx.x / 5;      // 16 tiles of 64 n
    const int ct = blockIdx.x % 5;      // 5 tiles of 16 c
    const int n0 = nt * 64, c0 = ct * 16;
    __shared__ float Pl[16 * 68];       // [c][k]
    __shared__ float Il[64 * 68];       // [k][n]
    const int ng = tid & 31, cg = tid >> 5;
    float acc[2][2] = {{0.f, 0.f}, {0.f, 0.f}};
    for (int kc = 0; kc < 256; kc += 64) {
      __syncthreads();
      for (int i = tid; i < 16 * 64; i += 256) {
        int k = i >> 4, c = i & 15;
        Pl[c * 68 + k] = proj_w[(kc + k) * 80 + c0 + c];
      }
      for (int i = tid; i < 64 * 64; i += 256) {
        int n = i >> 6, k = i & 63;
        Il[k * 68 + n] = in_proj_w[(n0 + n) * 256 + kc + k];
      }
      __syncthreads();
      for (int k = 0; k < 64; ++k) {
        float p0 = Pl[(cg * 2 + 0) * 68 + k];
        float p1 = Pl[(cg * 2 + 1) * 68 + k];
        float2 iv = *(const float2*)&Il[k * 68 + ng * 2];
        acc[0][0] = fmaf(p0, iv.x, acc[0][0]);
        acc[0][1] = fmaf(p0, iv.y, acc[0][1]);
        acc[1][0] = fmaf(p1, iv.x, acc[1][0]);
        acc[1][1] = fmaf(p1, iv.y, acc[1][1]);
      }
    }
    for (int r = 0; r < 2; ++r)
      for (int q = 0; q < 2; ++q)
        ws[OFF_W1T + (c0 + cg * 2 + r) * 1024 + n0 + ng * 2 + q] = acc[r][q];
  } else {
    int idx = (blockIdx.x - 80) * 256 + tid;
    if (idx < 1024) {
      float s = 0.f;
      for (int m = 0; m < 256; ++m) s = fmaf(in_proj_w[idx * 256 + m], proj_b[m], s);
      ws[OFF_B1 + idx] = s;
    } else if (idx < 1024 + 17920) {
      int j = idx - 1024;
      int n = j / 512, d = j - n * 512;
      float s = 0.f;
      for (int m = 0; m < 256; ++m) s = fmaf(fc_w[n * 256 + m], out_proj_w[m * 512 + d], s);
      ws[OFF_W2S + j] = s * 1e-3f;      // fold mean over T=1000
    } else if (idx < 1024 + 17920 + 8192) {
      int j = idx - (1024 + 17920);
      ws[OFF_AL2 + j] = -expf(A_log[j]);
    }
  }
}

// ================= K1: xz = X @ W1T + b1, x-tile in LDS (r7 proven form) ===
// Block = 256 threads = 256 consecutive n columns; 20-slot t-window
// (t0-4 .. t0+15) identical for the whole block. 80x20 x-tile (6.4KB) staged
// in LDS once; inner loop reads it via wave-uniform broadcast b128.
// Best of 6 structures tried (r3-r13): 45us, VGPR 36, highest occupancy.
__global__ __launch_bounds__(256) void k1_xz(const float* __restrict__ x,
                                             const float* __restrict__ conv_w,
                                             const float* __restrict__ conv_b,
                                             float* __restrict__ ws) {
  const int nt  = blockIdx.x;   // 4 tiles of 256 n
  const int tch = blockIdx.y;   // 63 chunks of 16 t
  const int b   = blockIdx.z;
  const int tid = threadIdx.x;
  const int n = nt * 256 + tid;        // global n column (0..1023)
  const int t0 = tch * 16;
  const int tbase = t0 - 4;            // acc[j] = xz at t = tbase + j

  __shared__ __align__(16) float xs[80 * 20];
  for (int i = tid; i < 1600; i += 256) {
    int k = i / 20, j = i - k * 20;
    int t = tbase + j;
    float v = 0.f;
    if (t >= 0 && t < 1000) v = x[(b * 80 + k) * 1000 + t];
    xs[i] = v;
  }
  __syncthreads();

  float acc[20];
  {
    const float b1v = ws[OFF_B1 + n];
#pragma unroll
    for (int j = 0; j < 20; ++j) acc[j] = b1v;
  }

  const float* __restrict__ w1t = ws + OFF_W1T;
  for (int kc = 0; kc < 80; kc += 8) {
    float wreg[8];
#pragma unroll
    for (int kk = 0; kk < 8; ++kk)
      wreg[kk] = w1t[(kc + kk) * 1024 + n];          // per-lane coalesced
#pragma unroll
    for (int kk = 0; kk < 8; ++kk) {
      const float w = wreg[kk];
      const float* xr = &xs[(kc + kk) * 20];         // uniform -> ds broadcast
#pragma unroll
      for (int g = 0; g < 5; ++g) {
        float4 xv = *(const float4*)(xr + g * 4);    // ds_read_b128
        acc[g * 4 + 0] = fmaf(xv.x, w, acc[g * 4 + 0]);
        acc[g * 4 + 1] = fmaf(xv.y, w, acc[g * 4 + 1]);
        acc[g * 4 + 2] = fmaf(xv.z, w, acc[g * 4 + 2]);
        acc[g * 4 + 3] = fmaf(xv.w, w, acc[g * 4 + 3]);
      }
    }
  }

  if (tch == 0) {
    // reference pads the PROJECTED sequence with zeros: xz[t<0] = 0
    acc[0] = 0.f; acc[1] = 0.f; acc[2] = 0.f; acc[3] = 0.f;
  }

  if (nt < 2) {
    // h-half: causal conv (taps t-3..t) + silu
    const int d = n;
    const float4 cw = *(const float4*)&conv_w[d * 4];
    const float cb = conv_b[d];
#pragma unroll
    for (int i = 0; i < 16; ++i) {
      int t = t0 + i;
      if (t < 1000) {
        float v = cb;
        v = fmaf(cw.x, acc[i + 1], v);   // xz[t-3]
        v = fmaf(cw.y, acc[i + 2], v);   // xz[t-2]
        v = fmaf(cw.z, acc[i + 3], v);   // xz[t-1]
        v = fmaf(cw.w, acc[i + 4], v);   // xz[t]
        ws[OFF_XH + (b * 1000 + t) * 512 + d] = silu_f(v);
      }
    }
  } else {
    const int d0 = n - 512;
#pragma unroll
    for (int i = 0; i < 16; ++i) {
      int t = t0 + i;
      if (t < 1000)
        ws[OFF_SZ + (b * 1000 + t) * 512 + d0] = silu_f(acc[i + 4]);
    }
  }
}

// ================= K2b: dbc partials = xh @ x_proj_w.T (split-K x2) =========
__global__ __launch_bounds__(256) void k2b_dbc(const float* __restrict__ x_proj_w,
                                               float* __restrict__ ws) {
  const int row0 = blockIdx.x * 16;
  const int ks   = blockIdx.y;          // K half
  const int k0   = ks * 256;
  __shared__ float Xl[16 * 68];
  __shared__ float Wl[48 * 68];
  const int tid = threadIdx.x;
  const int ng = tid & 15, rg = tid >> 4;
  float acc[3] = {0.f, 0.f, 0.f};
  for (int kc = 0; kc < 256; kc += 64) {
    __syncthreads();
    for (int i = tid; i < 16 * 64; i += 256) {
      int r = i >> 6, c = i & 63;
      Xl[r * 68 + c] = ws[OFF_XH + (row0 + r) * 512 + k0 + kc + c];
    }
    for (int i = tid; i < 48 * 64; i += 256) {
      int r = i >> 6, c = i & 63;
      Wl[r * 68 + c] = x_proj_w[r * 512 + k0 + kc + c];
    }
    __syncthreads();
    for (int c = 0; c < 64; c += 4) {
      float4 xa = *(const float4*)&Xl[rg * 68 + c];
      float4 w0 = *(const float4*)&Wl[(ng * 3 + 0) * 68 + c];
      float4 w1 = *(const float4*)&Wl[(ng * 3 + 1) * 68 + c];
      float4 w2 = *(const float4*)&Wl[(ng * 3 + 2) * 68 + c];
      acc[0] += xa.x*w0.x + xa.y*w0.y + xa.z*w0.z + xa.w*w0.w;
      acc[1] += xa.x*w1.x + xa.y*w1.y + xa.z*w1.z + xa.w*w1.w;
      acc[2] += xa.x*w2.x + xa.y*w2.y + xa.z*w2.z + xa.w*w2.w;
    }
  }
  for (int n = 0; n < 3; ++n)
    ws[OFF_DBCP + ks * 384000 + (row0 + rg) * 48 + ng * 3 + n] = acc[n];
}

// ================= K3: fused delta + scan, STATIC 50-t chunks ==============
// 20 chunks x 50 t (compile-time trip count -> unroll/software-pipelining;
// the runtime 63/62 bound kept VGPR at 32 = no load hoisting, latency-bound).
// block 512 = 64 d-lanes x 8 waves; TWO s-chains/thread (s = wv*2+{0,1}).
// grid (8 dg, 20 ck, 8 b) = 1280 blocks.
__global__ __launch_bounds__(512) void k3_scan1(const float* __restrict__ dt_proj_w,
                                                const float* __restrict__ dt_proj_b,
                                                float* __restrict__ ws) {
  const int dg = blockIdx.x;          // 8 groups of 64 d
  const int ck = blockIdx.y;          // 20 chunks of 50 t
  const int b  = blockIdx.z;
  const int tid = threadIdx.x;
  const int lane = tid & 63;
  const int wv = tid >> 6;
  const int d = dg * 64 + lane;
  const int rowbase = b * 1000 + ck * K3_NT;

  __shared__ __align__(16) float dbcl[K3_NT * 48];  // [t][dt(16)|B(16)|C(16)]
  __shared__ float dlt[K3_NT * 64];                 // [t][d-lane] delta
  for (int i = tid; i < K3_NT * 48; i += 512)
    dbcl[i] = ws[OFF_DBCP + rowbase * 48 + i] +
              ws[OFF_DBCP + 384000 + rowbase * 48 + i];
  __syncthreads();

  {
    const float4* wp = (const float4*)(dt_proj_w + d * 16);
    const float4 w0 = wp[0], w1 = wp[1], w2 = wp[2], w3 = wp[3];
    const float bias = dt_proj_b[d];
    for (int tt = wv; tt < K3_NT; tt += 8) {        // wave-strided, ~6-7 iters
      const float* dr = &dbcl[tt * 48];
      float4 q0 = *(const float4*)(dr + 0);         // b128 broadcasts
      float4 q1 = *(const float4*)(dr + 4);
      float4 q2 = *(const float4*)(dr + 8);
      float4 q3 = *(const float4*)(dr + 12);
      float lin = bias;
      lin = fmaf(q0.x, w0.x, lin); lin = fmaf(q0.y, w0.y, lin);
      lin = fmaf(q0.z, w0.z, lin); lin = fmaf(q0.w, w0.w, lin);
      lin = fmaf(q1.x, w1.x, lin); lin = fmaf(q1.y, w1.y, lin);
      lin = fmaf(q1.z, w1.z, lin); lin = fmaf(q1.w, w1.w, lin);
      lin = fmaf(q2.x, w2.x, lin); lin = fmaf(q2.y, w2.y, lin);
      lin = fmaf(q2.z, w2.z, lin); lin = fmaf(q2.w, w2.w, lin);
      lin = fmaf(q3.x, w3.x, lin); lin = fmaf(q3.y, w3.y, lin);
      lin = fmaf(q3.z, w3.z, lin); lin = fmaf(q3.w, w3.w, lin);
      dlt[tt * 64 + lane] = fmaxf(lin, 0.f) + log1pf(__expf(-fabsf(lin)));
    }
  }
  __syncthreads();

  const float2 av = *(const float2*)&ws[OFF_AL2 + d * 16 + wv * 2];
  const float a0 = av.x, a1 = av.y;
  const float* __restrict__ xhp = ws + OFF_XH + rowbase * 512 + d;
  const float* __restrict__ szp = ws + OFF_SZ + rowbase * 512 + d;
  float h0 = 0.f, h1 = 0.f, cp0 = 1.f, cp1 = 1.f;
  float S10 = 0.f, S11 = 0.f, S20 = 0.f, S21 = 0.f, xacc = 0.f;
#pragma unroll 5
  for (int i = 0; i < K3_NT; ++i) {                 // STATIC bound
    float del = dlt[i * 64 + lane];
    float xh  = xhp[i * 512];
    float sz  = szp[i * 512];
    float2 bB = *(const float2*)&dbcl[i * 48 + 16 + wv * 2];
    float2 bC = *(const float2*)&dbcl[i * 48 + 32 + wv * 2];
    float du = del * xh;
    xacc = fmaf(xh, sz, xacc);
    float e0 = __expf(del * a0), e1 = __expf(del * a1);
    cp0 *= e0; cp1 *= e1;
    h0 = fmaf(e0, h0, du * bB.x);
    h1 = fmaf(e1, h1, du * bB.y);
    float cs0 = bC.x * sz, cs1 = bC.y * sz;
    S10 = fmaf(h0, cs0, S10); S11 = fmaf(h1, cs1, S11);
    S20 = fmaf(cp0, cs0, S20); S21 = fmaf(cp1, cs1, S21);
  }
  {
    const int cbase = CHUNK_BASE(ck);
    const int s = wv * 2;
    int idx = (b * 16 + s) * 512 + d;
    *(float4*)&ws[cbase + idx * 4] = make_float4(cp0, h0, S10, S20);
    *(float4*)&ws[cbase + (idx + 512) * 4] = make_float4(cp1, h1, S11, S21);
  }
  if (wv == 0) ws[OFF_ACC20 + (ck * 8 + b) * 512 + d] = xacc;
}

// ================= K4: combine 20 chunks + s-reduce -> ybar =================
__global__ __launch_bounds__(256) void k4_scan2(const float* __restrict__ Dvec,
                                                float* __restrict__ ws) {
  const int dg = blockIdx.x;   // 32 groups of 16 d
  const int b  = blockIdx.y;
  const int tid = threadIdx.x;
  const int dl = tid & 15, s = tid >> 4;
  const int d = dg * 16 + dl;
  const int lane = tid & 63, wv = tid >> 6;
  float h = 0.f, y = 0.f;
#pragma unroll
  for (int k = 0; k < 20; ++k) {
    const float4 f = *(const float4*)&ws[CHUNK_BASE(k) + ((b * 16 + s) * 512 + d) * 4];
    y = fmaf(f.w, h, y + f.z);   // S1 + S2*h_in
    h = fmaf(f.x, h, f.y);       // P*h_in + q
  }
  y += __shfl_xor(y, 16);
  y += __shfl_xor(y, 32);
  __shared__ float ys[4][16];
  if (lane < 16) ys[wv][dl] = y;
  __syncthreads();
  if (tid < 16) {
    float yt = ys[0][tid] + ys[1][tid] + ys[2][tid] + ys[3][tid];
    float acc = 0.f;
#pragma unroll
    for (int k = 0; k < 20; ++k) acc += ws[OFF_ACC20 + (k * 8 + b) * 512 + dg * 16 + tid];
    int dd = dg * 16 + tid;
    ws[OFF_YBAR + b * 512 + dd] = yt + Dvec[dd] * acc;
  }
}

// ================= K5: out = ybar @ W2s.T + fc_b =================
__global__ __launch_bounds__(64) void k5_out(const float* __restrict__ fc_b,
                                             const float* __restrict__ ws,
                                             float* __restrict__ out) {
  const int b = blockIdx.x;
  const int n = threadIdx.x;
  if (n >= 35) return;
  const float* yb = ws + OFF_YBAR + b * 512;
  const float* w  = ws + OFF_W2S + n * 512;
  float sum = 0.f;
#pragma unroll 8
  for (int k = 0; k < 512; ++k) sum = fmaf(yb[k], w[k], sum);
  out[b * 35 + n] = sum + fc_b[n];
}

extern "C" void kernel_launch(void* const* d_in, const int* in_sizes, int n_in,
                              void* d_out, int out_size, void* d_ws, size_t ws_size,
                              hipStream_t stream) {
  const float* x          = (const float*)d_in[0];
  const float* proj_w     = (const float*)d_in[1];
  const float* proj_b     = (const float*)d_in[2];
  const float* in_proj_w  = (const float*)d_in[3];
  const float* conv_w     = (const float*)d_in[4];
  const float* conv_b     = (const float*)d_in[5];
  const float* x_proj_w   = (const float*)d_in[6];
  const float* dt_proj_w  = (const float*)d_in[7];
  const float* dt_proj_b  = (const float*)d_in[8];
  const float* A_log      = (const float*)d_in[9];
  const float* Dvec       = (const float*)d_in[10];
  const float* out_proj_w = (const float*)d_in[11];
  const float* fc_w       = (const float*)d_in[12];
  const float* fc_b       = (const float*)d_in[13];
  float* ws  = (float*)d_ws;
  float* out = (float*)d_out;
  if (ws_size < (size_t)WS_FLOATS * sizeof(float)) return;  // need ~76 MB scratch

  prep_all  <<<186,             256, 0, stream>>>(proj_w, proj_b, in_proj_w, fc_w,
                                                  out_proj_w, A_log, ws);
  k1_xz     <<<dim3(4, 63, 8),  256, 0, stream>>>(x, conv_w, conv_b, ws);
  k2b_dbc   <<<dim3(500, 2),    256, 0, stream>>>(x_proj_w, ws);
  k3_scan1  <<<dim3(8, 20, 8),  512, 0, stream>>>(dt_proj_w, dt_proj_b, ws);
  k4_scan2  <<<dim3(32, 8),     256, 0, stream>>>(Dvec, ws);
  k5_out    <<<8,               64,  0, stream>>>(fc_b, ws, out);
}